// Round 2
// baseline (126.760 us; speedup 1.0000x reference)
//
#include <hip/hip_runtime.h>
#include <hip/hip_bf16.h>

typedef __attribute__((ext_vector_type(8))) short short8;
typedef __attribute__((ext_vector_type(4))) float floatx4;

__device__ __forceinline__ short tobf16(float f) {
    unsigned u = __builtin_bit_cast(unsigned, f);
    u += 0x7fffu + ((u >> 16) & 1u);   // round-to-nearest-even
    return (short)(u >> 16);
}
__device__ __forceinline__ float bf2f(unsigned s) {
    return __builtin_bit_cast(float, s << 16);
}

// ---------------------------------------------------------------------------
// Kernel 1: P[v][h] = sum_d E[v][d] * W1[d][h]   (V x 300) @ (300 x 32) -> bf16
// Block = 256 threads = 4 waves; each wave one 16-row tile (MFMA 16x16x32 bf16,
// K padded 300->320, tail masked). W1 staged ONCE per block into LDS in
// frag-major order: lane l reads its B-frag at base + 16*l (conflict-free b128).
// ---------------------------------------------------------------------------
__global__ __launch_bounds__(256) void project_kernel(
        const float* __restrict__ E, const float* __restrict__ W1,
        unsigned short* __restrict__ P, int V) {
    // frag-major W1 as bf16: element e = (((s*2+t)*4+q)*16+m)*8 + j
    //   k = s*32 + q*8 + j  (zero for k>=300),  n = t*16 + m
    __shared__ short w1f[10240];
    for (int e = threadIdx.x; e < 10240; e += 256) {
        int j  = e & 7;
        int f  = e >> 3;
        int m  = f & 15;
        int q  = (f >> 4) & 3;
        int st = f >> 6;           // s*2 + t
        int t  = st & 1, s = st >> 1;
        int k  = s * 32 + q * 8 + j;
        int n  = t * 16 + m;
        float w = (k < 300) ? W1[k * 32 + n] : 0.f;
        w1f[e] = tobf16(w);
    }
    __syncthreads();

    int lane = threadIdx.x & 63;
    int w    = threadIdx.x >> 6;
    int m    = lane & 15;
    int quad = lane >> 4;

    short8 bfrag[10][2];
#pragma unroll
    for (int s = 0; s < 10; ++s)
#pragma unroll
        for (int t = 0; t < 2; ++t)
            bfrag[s][t] = *(const short8*)&w1f[((((s * 2 + t) * 4 + quad) * 16 + m) * 8)];

    int tile = blockIdx.x * 4 + w;
    int v0   = tile << 4;
    if (v0 >= V) return;

    const float* arow = E + (size_t)(v0 + m) * 300;
    floatx4 acc0 = {0.f, 0.f, 0.f, 0.f};
    floatx4 acc1 = {0.f, 0.f, 0.f, 0.f};

#pragma unroll
    for (int s = 0; s < 9; ++s) {   // k0 = 0..256, all columns < 300
        floatx4 f0 = *(const floatx4*)(arow + s * 32 + quad * 8);
        floatx4 f1 = *(const floatx4*)(arow + s * 32 + quad * 8 + 4);
        short8 a;
        a[0] = tobf16(f0[0]); a[1] = tobf16(f0[1]);
        a[2] = tobf16(f0[2]); a[3] = tobf16(f0[3]);
        a[4] = tobf16(f1[0]); a[5] = tobf16(f1[1]);
        a[6] = tobf16(f1[2]); a[7] = tobf16(f1[3]);
        acc0 = __builtin_amdgcn_mfma_f32_16x16x32_bf16(a, bfrag[s][0], acc0, 0, 0, 0);
        acc1 = __builtin_amdgcn_mfma_f32_16x16x32_bf16(a, bfrag[s][1], acc1, 0, 0, 0);
    }
    {   // s = 9: k0 = 288, mask columns >= 300 (B is zero there anyway)
        short8 a;
#pragma unroll
        for (int j = 0; j < 8; ++j) {
            int c = 288 + quad * 8 + j;
            a[j] = (c < 300) ? tobf16(arow[c]) : (short)0;
        }
        acc0 = __builtin_amdgcn_mfma_f32_16x16x32_bf16(a, bfrag[9][0], acc0, 0, 0, 0);
        acc1 = __builtin_amdgcn_mfma_f32_16x16x32_bf16(a, bfrag[9][1], acc1, 0, 0, 0);
    }

    // C/D layout: col = lane&15, row = quad*4 + reg
#pragma unroll
    for (int r = 0; r < 4; ++r) {
        int row = v0 + quad * 4 + r;
        P[(size_t)row * 32 + m]      = (unsigned short)tobf16(acc0[r]);
        P[(size_t)row * 32 + 16 + m] = (unsigned short)tobf16(acc1[r]);
    }
}

// ---------------------------------------------------------------------------
// Kernel 2: per batch row b: acc[h] = sum_l P[x[b,l]][h]; then tiny MLP.
// Block = 256 = 4 waves. Wave handles ~L/4 tokens, 4 tokens per iteration:
// lane group g = lane>>4 takes token t+g; lane i = lane&15 reads bf16 pair
// (h=2i, 2i+1) -> one contiguous 64 B row per 16-lane group.
// ---------------------------------------------------------------------------
__global__ __launch_bounds__(256) void pool_mlp_kernel(
        const int* __restrict__ x, const int* __restrict__ lengths,
        const unsigned short* __restrict__ P, const float* __restrict__ b1,
        const float* __restrict__ W2, const float* __restrict__ b2,
        float* __restrict__ out, int L, int C) {
    __shared__ int   xs[512];
    __shared__ float red[4][16][2];
    int b    = blockIdx.x;
    int w    = threadIdx.x >> 6;
    int lane = threadIdx.x & 63;
    int i    = lane & 15;     // h-pair index
    int g    = lane >> 4;     // token subgroup

    const int* xrow = x + (size_t)b * L;
    for (int t = threadIdx.x; t < L; t += 256) xs[t] = xrow[t];
    __syncthreads();

    int Lw    = (L + 3) >> 2;
    int start = w * Lw;
    int end   = min(start + Lw, L);

    float a0 = 0.f, a1 = 0.f;
    for (int t = start; t < end; t += 4) {
        int tt = t + g;
        if (tt < end) {
            int idx = xs[tt];
            unsigned pk = *(const unsigned*)(P + (size_t)idx * 32 + 2 * i);
            a0 += bf2f(pk & 0xffffu);
            a1 += bf2f(pk >> 16);
        }
    }
    a0 += __shfl_xor(a0, 32, 64);  a1 += __shfl_xor(a1, 32, 64);
    a0 += __shfl_xor(a0, 16, 64);  a1 += __shfl_xor(a1, 16, 64);
    if (lane < 16) { red[w][i][0] = a0; red[w][i][1] = a1; }
    __syncthreads();

    if (threadIdx.x < 16) {
        float s0 = red[0][i][0] + red[1][i][0] + red[2][i][0] + red[3][i][0];
        float s1 = red[0][i][1] + red[1][i][1] + red[2][i][1] + red[3][i][1];
        float inv = 1.f / (float)lengths[b];
        float h0 = fmaxf(s0 * inv + b1[2 * i], 0.f);
        float h1 = fmaxf(s1 * inv + b1[2 * i + 1], 0.f);
        for (int c = 0; c < C; ++c) {
            float p = h0 * W2[(2 * i) * C + c] + h1 * W2[(2 * i + 1) * C + c];
            p += __shfl_xor(p, 8, 64);
            p += __shfl_xor(p, 4, 64);
            p += __shfl_xor(p, 2, 64);
            p += __shfl_xor(p, 1, 64);
            if (threadIdx.x == 0) out[(size_t)b * C + c] = p + b2[c];
        }
    }
}

// Generic fallback (unexpected shapes or too-small workspace): correct, not fast.
__global__ void naive_dnn(const int* __restrict__ x, const int* __restrict__ len,
                          const float* __restrict__ emb, const float* __restrict__ W1,
                          const float* __restrict__ b1, const float* __restrict__ W2,
                          const float* __restrict__ b2, float* __restrict__ out,
                          int L, int V, int D, int H, int C) {
    __shared__ float srep[2048];
    __shared__ float sh[256];
    int b = blockIdx.x;
    float lenf = (float)len[b];
    for (int d = threadIdx.x; d < D; d += blockDim.x) {
        float acc = 0.f;
        for (int l = 0; l < L; ++l) {
            int idx = x[(size_t)b * L + l];
            acc += emb[(size_t)idx * D + d];
        }
        srep[d] = acc / lenf;
    }
    __syncthreads();
    for (int hh = threadIdx.x; hh < H; hh += blockDim.x) {
        float a = b1[hh];
        for (int d = 0; d < D; ++d) a += srep[d] * W1[(size_t)d * H + hh];
        sh[hh] = fmaxf(a, 0.f);
    }
    __syncthreads();
    for (int c = threadIdx.x; c < C; c += blockDim.x) {
        float a = b2[c];
        for (int hh = 0; hh < H; ++hh) a += sh[hh] * W2[hh * C + c];
        out[(size_t)b * C + c] = a;
    }
}

extern "C" void kernel_launch(void* const* d_in, const int* in_sizes, int n_in,
                              void* d_out, int out_size, void* d_ws, size_t ws_size,
                              hipStream_t stream) {
    const int*   x       = (const int*)d_in[0];
    const int*   lengths = (const int*)d_in[1];
    const float* emb     = (const float*)d_in[2];
    const float* W1      = (const float*)d_in[3];
    const float* b1      = (const float*)d_in[4];
    const float* W2      = (const float*)d_in[5];
    const float* b2      = (const float*)d_in[6];
    float* out = (float*)d_out;

    int B = in_sizes[1];
    int L = in_sizes[0] / B;
    int H = in_sizes[4];
    int C = in_sizes[6];
    int D = in_sizes[3] / H;
    int V = in_sizes[2] / D;

    bool fast = (D == 300) && (H == 32) && ((V & 15) == 0) && (L <= 512) &&
                (ws_size >= (size_t)V * H * sizeof(unsigned short));
    if (fast) {
        unsigned short* P = (unsigned short*)d_ws;
        int tiles  = V >> 4;                       // 3125
        int blocks = (tiles + 3) / 4;              // 4 wave-tiles per block
        project_kernel<<<blocks, 256, 0, stream>>>(emb, W1, P, V);
        pool_mlp_kernel<<<B, 256, 0, stream>>>(x, lengths, P, b1, W2, b2, out, L, C);
    } else {
        naive_dnn<<<B, 256, 0, stream>>>(x, lengths, emb, W1, b1, W2, b2, out,
                                         L, V, D, H, C);
    }
}

// Round 3
// 126.350 us; speedup vs baseline: 1.0032x; 1.0032x over previous
//
#include <hip/hip_runtime.h>
#include <hip/hip_bf16.h>

typedef __attribute__((ext_vector_type(8))) short short8;
typedef __attribute__((ext_vector_type(4))) float floatx4;

__device__ __forceinline__ short tobf16(float f) {
    unsigned u = __builtin_bit_cast(unsigned, f);
    u += 0x7fffu + ((u >> 16) & 1u);   // round-to-nearest-even
    return (short)(u >> 16);
}
__device__ __forceinline__ float bf2f(unsigned s) {
    return __builtin_bit_cast(float, s << 16);
}
// async 16B/lane global->LDS DMA; lds base must be wave-uniform (HW adds lane*16)
__device__ __forceinline__ void async_copy16(const void* g, void* l) {
    __builtin_amdgcn_global_load_lds(
        (const __attribute__((address_space(1))) void*)g,
        (__attribute__((address_space(3))) void*)l, 16, 0, 0);
}

// ---------------------------------------------------------------------------
// Kernel 1: P[v][h] = sum_d E[v][d] * W1[d][h]   (V x 300) @ (300 x 32) -> bf16
// Block = 256 = 4 waves. Block g owns 64 consecutive rows of E (4 MFMA tiles,
// one per wave). The 64x300 fp32 slab (76,800 B, contiguous in memory) is
// DMA'd into LDS via global_load_lds (16 B/lane, flat copy, no VGPR cost);
// waves then build A-frags from LDS and MFMA against register-resident W1.
// LDS 76.8 KB -> 2 blocks/CU; DMA in flight ~150 KB/CU >> latency-hiding bar.
// ---------------------------------------------------------------------------
__global__ __launch_bounds__(256) void project_kernel(
        const float* __restrict__ E, const float* __restrict__ W1,
        unsigned short* __restrict__ P, int V) {
    __shared__ char lds[76816];          // 64 rows x 300 fp32 (+pad)
    short* w1f  = (short*)lds;           // phase 1: frag-major W1 (20 KB)
    float* bufF = (float*)lds;           // phase 2: E slab

    int tid  = threadIdx.x;
    int lane = tid & 63;
    int w    = tid >> 6;                 // wave id 0..3
    int m    = lane & 15;
    int quad = lane >> 4;

    // --- phase 1: W1 -> LDS frag-major bf16, then -> registers ---
    // element e = (((s*2+t)*4+q)*16+mm)*8 + j ;  k = s*32+q*8+j, n = t*16+mm
    for (int e = tid; e < 10240; e += 256) {
        int j  = e & 7;
        int f  = e >> 3;
        int mm = f & 15;
        int q  = (f >> 4) & 3;
        int st = f >> 6;
        int t  = st & 1, s = st >> 1;
        int k  = s * 32 + q * 8 + j;
        int n  = t * 16 + mm;
        float wv = (k < 300) ? W1[k * 32 + n] : 0.f;
        w1f[e] = tobf16(wv);
    }
    __syncthreads();

    short8 bfrag[10][2];
#pragma unroll
    for (int s = 0; s < 10; ++s)
#pragma unroll
        for (int t = 0; t < 2; ++t)
            bfrag[s][t] = *(const short8*)&w1f[((((s * 2 + t) * 4 + quad) * 16 + m) * 8)];
    __syncthreads();                     // w1f region about to be overwritten

    // --- phase 2: DMA the 64-row slab into LDS ---
    int g    = blockIdx.x;
    int rows = min(64, V - g * 64);
    int bytes = rows * 1200;             // multiple of 16
    const char* gbase = (const char*)E + (size_t)g * 76800;
    int nchunks = (bytes + 1023) >> 10;  // 1024-B chunks (64 lanes x 16 B)
    for (int c = w; c < nchunks; c += 4) {
        int off = (c << 10) + lane * 16;
        if (off < bytes) async_copy16(gbase + off, lds + (c << 10));
    }
    __syncthreads();                     // compiler drains vmcnt here

    // --- phase 3: MFMA from LDS ---
    int tile = g * 4 + w;
    if (tile * 16 < V) {
        int rowbase = (w * 16 + m) * 300;
        floatx4 acc0 = {0.f, 0.f, 0.f, 0.f};
        floatx4 acc1 = {0.f, 0.f, 0.f, 0.f};
#pragma unroll
        for (int s = 0; s < 9; ++s) {    // cols 0..287, all valid
            floatx4 f0 = *(const floatx4*)&bufF[rowbase + s * 32 + quad * 8];
            floatx4 f1 = *(const floatx4*)&bufF[rowbase + s * 32 + quad * 8 + 4];
            short8 a;
            a[0] = tobf16(f0[0]); a[1] = tobf16(f0[1]);
            a[2] = tobf16(f0[2]); a[3] = tobf16(f0[3]);
            a[4] = tobf16(f1[0]); a[5] = tobf16(f1[1]);
            a[6] = tobf16(f1[2]); a[7] = tobf16(f1[3]);
            acc0 = __builtin_amdgcn_mfma_f32_16x16x32_bf16(a, bfrag[s][0], acc0, 0, 0, 0);
            acc1 = __builtin_amdgcn_mfma_f32_16x16x32_bf16(a, bfrag[s][1], acc1, 0, 0, 0);
        }
        {   // s = 9: cols 288..303, zero-mask cols >= 300 (avoid NaN*0)
            short8 a;
#pragma unroll
            for (int j = 0; j < 8; ++j) {
                int c = 288 + quad * 8 + j;
                a[j] = (c < 300) ? tobf16(bufF[rowbase + c]) : (short)0;
            }
            acc0 = __builtin_amdgcn_mfma_f32_16x16x32_bf16(a, bfrag[9][0], acc0, 0, 0, 0);
            acc1 = __builtin_amdgcn_mfma_f32_16x16x32_bf16(a, bfrag[9][1], acc1, 0, 0, 0);
        }
        // C/D layout: col = lane&15, row = quad*4 + reg
#pragma unroll
        for (int r = 0; r < 4; ++r) {
            int row = tile * 16 + quad * 4 + r;
            P[(size_t)row * 32 + m]      = (unsigned short)tobf16(acc0[r]);
            P[(size_t)row * 32 + 16 + m] = (unsigned short)tobf16(acc1[r]);
        }
    }
}

// ---------------------------------------------------------------------------
// Kernel 2: per batch row b: acc[h] = sum_l P[x[b,l]][h]; then tiny MLP.
// Block = 256 = 4 waves; 4 tokens/iteration; bf16x2 packed gathers (64 B/row).
// ---------------------------------------------------------------------------
__global__ __launch_bounds__(256) void pool_mlp_kernel(
        const int* __restrict__ x, const int* __restrict__ lengths,
        const unsigned short* __restrict__ P, const float* __restrict__ b1,
        const float* __restrict__ W2, const float* __restrict__ b2,
        float* __restrict__ out, int L, int C) {
    __shared__ int   xs[512];
    __shared__ float red[4][16][2];
    int b    = blockIdx.x;
    int w    = threadIdx.x >> 6;
    int lane = threadIdx.x & 63;
    int i    = lane & 15;     // h-pair index
    int g    = lane >> 4;     // token subgroup

    const int* xrow = x + (size_t)b * L;
    for (int t = threadIdx.x; t < L; t += 256) xs[t] = xrow[t];
    __syncthreads();

    int Lw    = (L + 3) >> 2;
    int start = w * Lw;
    int end   = min(start + Lw, L);

    float a0 = 0.f, a1 = 0.f;
    for (int t = start; t < end; t += 4) {
        int tt = t + g;
        if (tt < end) {
            int idx = xs[tt];
            unsigned pk = *(const unsigned*)(P + (size_t)idx * 32 + 2 * i);
            a0 += bf2f(pk & 0xffffu);
            a1 += bf2f(pk >> 16);
        }
    }
    a0 += __shfl_xor(a0, 32, 64);  a1 += __shfl_xor(a1, 32, 64);
    a0 += __shfl_xor(a0, 16, 64);  a1 += __shfl_xor(a1, 16, 64);
    if (lane < 16) { red[w][i][0] = a0; red[w][i][1] = a1; }
    __syncthreads();

    if (threadIdx.x < 16) {
        float s0 = red[0][i][0] + red[1][i][0] + red[2][i][0] + red[3][i][0];
        float s1 = red[0][i][1] + red[1][i][1] + red[2][i][1] + red[3][i][1];
        float inv = 1.f / (float)lengths[b];
        float h0 = fmaxf(s0 * inv + b1[2 * i], 0.f);
        float h1 = fmaxf(s1 * inv + b1[2 * i + 1], 0.f);
        for (int c = 0; c < C; ++c) {
            float p = h0 * W2[(2 * i) * C + c] + h1 * W2[(2 * i + 1) * C + c];
            p += __shfl_xor(p, 8, 64);
            p += __shfl_xor(p, 4, 64);
            p += __shfl_xor(p, 2, 64);
            p += __shfl_xor(p, 1, 64);
            if (threadIdx.x == 0) out[(size_t)b * C + c] = p + b2[c];
        }
    }
}

// Generic fallback (unexpected shapes or too-small workspace): correct, not fast.
__global__ void naive_dnn(const int* __restrict__ x, const int* __restrict__ len,
                          const float* __restrict__ emb, const float* __restrict__ W1,
                          const float* __restrict__ b1, const float* __restrict__ W2,
                          const float* __restrict__ b2, float* __restrict__ out,
                          int L, int V, int D, int H, int C) {
    __shared__ float srep[2048];
    __shared__ float sh[256];
    int b = blockIdx.x;
    float lenf = (float)len[b];
    for (int d = threadIdx.x; d < D; d += blockDim.x) {
        float acc = 0.f;
        for (int l = 0; l < L; ++l) {
            int idx = x[(size_t)b * L + l];
            acc += emb[(size_t)idx * D + d];
        }
        srep[d] = acc / lenf;
    }
    __syncthreads();
    for (int hh = threadIdx.x; hh < H; hh += blockDim.x) {
        float a = b1[hh];
        for (int d = 0; d < D; ++d) a += srep[d] * W1[(size_t)d * H + hh];
        sh[hh] = fmaxf(a, 0.f);
    }
    __syncthreads();
    for (int c = threadIdx.x; c < C; c += blockDim.x) {
        float a = b2[c];
        for (int hh = 0; hh < H; ++hh) a += sh[hh] * W2[hh * C + c];
        out[(size_t)b * C + c] = a;
    }
}

extern "C" void kernel_launch(void* const* d_in, const int* in_sizes, int n_in,
                              void* d_out, int out_size, void* d_ws, size_t ws_size,
                              hipStream_t stream) {
    const int*   x       = (const int*)d_in[0];
    const int*   lengths = (const int*)d_in[1];
    const float* emb     = (const float*)d_in[2];
    const float* W1      = (const float*)d_in[3];
    const float* b1      = (const float*)d_in[4];
    const float* W2      = (const float*)d_in[5];
    const float* b2      = (const float*)d_in[6];
    float* out = (float*)d_out;

    int B = in_sizes[1];
    int L = in_sizes[0] / B;
    int H = in_sizes[4];
    int C = in_sizes[6];
    int D = in_sizes[3] / H;
    int V = in_sizes[2] / D;

    bool fast = (D == 300) && (H == 32) && ((V & 15) == 0) && (L <= 512) &&
                (ws_size >= (size_t)V * H * sizeof(unsigned short));
    if (fast) {
        unsigned short* P = (unsigned short*)d_ws;
        int blocks = (V + 63) / 64;                // 64 rows (4 tiles) per block
        project_kernel<<<blocks, 256, 0, stream>>>(emb, W1, P, V);
        pool_mlp_kernel<<<B, 256, 0, stream>>>(x, lengths, P, b1, W2, b2, out, L, C);
    } else {
        naive_dnn<<<B, 256, 0, stream>>>(x, lengths, emb, W1, b1, W2, b2, out,
                                         L, V, D, H, C);
    }
}